// Round 3
// baseline (908.320 us; speedup 1.0000x reference)
//
#include <hip/hip_runtime.h>
#include <math.h>

#define NROWS 1024
#define DCOLS 16384
#define NTOT  16777216
#define BINS  1000

// ---------------- K1: per-row sum / sumsq / min / max (fp64 accumulation) ----------------
__global__ __launch_bounds__(256) void k_rowstats(const float* __restrict__ x,
    double* __restrict__ rowsum, double* __restrict__ rowsumsq,
    double* __restrict__ rowmin, double* __restrict__ rowmax) {
  const int row = blockIdx.x;
  const int t = threadIdx.x;
  const float4* xr = (const float4*)(x + (size_t)row * DCOLS);
  double s = 0.0, s2 = 0.0;
  float mn = 3.4028235e38f, mx = -3.4028235e38f;
  for (int j = t; j < DCOLS / 4; j += 256) {
    float4 v = xr[j];
    double a = v.x, b = v.y, c = v.z, d = v.w;
    s  += (a + b) + (c + d);
    s2 += (a * a + b * b) + (c * c + d * d);
    mn = fminf(mn, fminf(fminf(v.x, v.y), fminf(v.z, v.w)));
    mx = fmaxf(mx, fmaxf(fmaxf(v.x, v.y), fmaxf(v.z, v.w)));
  }
  #pragma unroll
  for (int off = 32; off > 0; off >>= 1) {
    s  += __shfl_down(s, off);
    s2 += __shfl_down(s2, off);
    mn = fminf(mn, __shfl_down(mn, off));
    mx = fmaxf(mx, __shfl_down(mx, off));
  }
  __shared__ double lsd[8];
  __shared__ float  lsf[8];
  const int lane = t & 63, w = t >> 6;
  if (lane == 0) { lsd[w] = s; lsd[4 + w] = s2; lsf[w] = mn; lsf[4 + w] = mx; }
  __syncthreads();
  if (t == 0) {
    rowsum[row]   = (lsd[0] + lsd[1]) + (lsd[2] + lsd[3]);
    rowsumsq[row] = (lsd[4] + lsd[5]) + (lsd[6] + lsd[7]);
    rowmin[row] = (double)fminf(fminf(lsf[0], lsf[1]), fminf(lsf[2], lsf[3]));
    rowmax[row] = (double)fmaxf(fmaxf(lsf[4], lsf[5]), fmaxf(lsf[6], lsf[7]));
  }
}

// ---------------- K2: global scalars (fp64 stats -> float32 np-style scalars) ----------------
__global__ __launch_bounds__(256) void k_stats2(
    const double* __restrict__ rowsum, const double* __restrict__ rowsumsq,
    const double* __restrict__ rowmin, const double* __restrict__ rowmax,
    double* __restrict__ m, double* __restrict__ dn, float* __restrict__ fscal) {
#pragma clang fp contract(off)
  const int t = threadIdx.x;
  double s = 0.0, s2 = 0.0, mn = 1e300, mx = -1e300;
  for (int r = t; r < NROWS; r += 256) {
    s += rowsum[r]; s2 += rowsumsq[r];
    mn = fmin(mn, rowmin[r]); mx = fmax(mx, rowmax[r]);
  }
  #pragma unroll
  for (int off = 32; off > 0; off >>= 1) {
    s  += __shfl_down(s, off);
    s2 += __shfl_down(s2, off);
    mn = fmin(mn, __shfl_down(mn, off));
    mx = fmax(mx, __shfl_down(mx, off));
  }
  __shared__ double lsd[16];
  const int lane = t & 63, w = t >> 6;
  if (lane == 0) { lsd[w] = s; lsd[4 + w] = s2; lsd[8 + w] = mn; lsd[12 + w] = mx; }
  __syncthreads();
  if (t == 0) {
    double S  = (lsd[0] + lsd[1]) + (lsd[2] + lsd[3]);
    double S2 = (lsd[4] + lsd[5]) + (lsd[6] + lsd[7]);
    double MN = fmin(fmin(lsd[8], lsd[9]), fmin(lsd[10], lsd[11]));
    double MX = fmax(fmax(lsd[12], lsd[13]), fmax(lsd[14], lsd[15]));
    const double N = 16777216.0;
    double mu  = S / N;
    double var = (S2 - S * S / N) / (N - 1.0);
    double sig = sqrt(var);
    // ---- float32 scalar chain, replicating np float32 semantics ----
    float mu32 = (float)mu;
    float sg32 = (float)sig;
    float mnf  = (float)MN;       // exact (value is a float32)
    float mxf  = (float)MX;
    float lof  = (mnf - mu32) / sg32;   // == min(tnorm) by monotonicity
    float hif  = (mxf - mu32) / sg32;
    float wf   = (hif - lof) / 1000.0f;
    fscal[0] = mu32;
    fscal[1] = sg32;
    fscal[2] = lof;
    fscal[3] = wf;
    fscal[4] = 16384.0f * wf;        // n*width (local), f32 product like np
    fscal[5] = 16777216.0f * wf;     // n*width (batch)
  }
  __syncthreads();
  for (int r = t; r < NROWS; r += 256) {
    double rs = rowsum[r];
    m[r]  = rs / 16384.0;
    dn[r] = sqrt(rowsumsq[r] - rs * rs * (1.0 / 16384.0));
  }
}

// ---------------- K5: Gram GEMM (fp32 FMA, fp64 chunk fold) + |corr| row-partials ----------------
__global__ __launch_bounds__(256) void k_gram(const float* __restrict__ x,
    const double* __restrict__ m, const double* __restrict__ dn,
    double* __restrict__ fpart) {
  __shared__ float As[32][72];
  __shared__ float Bs[32][72];
  __shared__ double red[64][16];
  const int t = threadIdx.x;
  const int bi = blockIdx.y, bj = blockIdx.x;
  const int tx = t & 15, ty = t >> 4;
  const int lr = t >> 2, lc = t & 3;
  const float* Ap = x + (size_t)(bi * 64 + lr) * DCOLS;
  const float* Bp = x + (size_t)(bj * 64 + lr) * DCOLS;
  double acc[4][4];
  #pragma unroll
  for (int i = 0; i < 4; ++i)
    #pragma unroll
    for (int j = 0; j < 4; ++j) acc[i][j] = 0.0;

  // prefetch chunk 0
  float4 a0 = ((const float4*)Ap)[lc];
  float4 a1 = ((const float4*)Ap)[lc + 4];
  float4 b0 = ((const float4*)Bp)[lc];
  float4 b1 = ((const float4*)Bp)[lc + 4];

  for (int k0 = 0; k0 < DCOLS; k0 += 32) {
    __syncthreads();   // previous chunk's LDS reads done
    {
      const float* a0p = (const float*)&a0;
      const float* a1p = (const float*)&a1;
      const float* b0p = (const float*)&b0;
      const float* b1p = (const float*)&b1;
      #pragma unroll
      for (int jj = 0; jj < 4; ++jj) {
        As[lc * 4 + jj][lr]      = a0p[jj];
        As[16 + lc * 4 + jj][lr] = a1p[jj];
        Bs[lc * 4 + jj][lr]      = b0p[jj];
        Bs[16 + lc * 4 + jj][lr] = b1p[jj];
      }
    }
    __syncthreads();
    if (k0 + 32 < DCOLS) {   // prefetch next chunk; latency hides under FMAs
      a0 = ((const float4*)(Ap + k0 + 32))[lc];
      a1 = ((const float4*)(Ap + k0 + 32))[lc + 4];
      b0 = ((const float4*)(Bp + k0 + 32))[lc];
      b1 = ((const float4*)(Bp + k0 + 32))[lc + 4];
    }
    float ac[4][4];
    #pragma unroll
    for (int i = 0; i < 4; ++i)
      #pragma unroll
      for (int j = 0; j < 4; ++j) ac[i][j] = 0.0f;
    #pragma unroll
    for (int k = 0; k < 32; ++k) {
      const float4 av = *(const float4*)&As[k][ty * 4];
      const float4 bv = *(const float4*)&Bs[k][tx * 4];
      const float aa[4] = {av.x, av.y, av.z, av.w};
      const float bb[4] = {bv.x, bv.y, bv.z, bv.w};
      #pragma unroll
      for (int i = 0; i < 4; ++i)
        #pragma unroll
        for (int j = 0; j < 4; ++j)
          ac[i][j] += aa[i] * bb[j];
    }
    #pragma unroll
    for (int i = 0; i < 4; ++i)
      #pragma unroll
      for (int j = 0; j < 4; ++j) acc[i][j] += (double)ac[i][j];
  }

  // epilogue: cov = G - D*m_i*m_j ; partial_i = sum_j |cov| / d_j
  double mr[4], mc[4], dc[4];
  #pragma unroll
  for (int i = 0; i < 4; ++i) mr[i] = m[bi * 64 + ty * 4 + i];
  #pragma unroll
  for (int j = 0; j < 4; ++j) {
    int col = bj * 64 + tx * 4 + j;
    mc[j] = m[col]; dc[j] = dn[col];
  }
  #pragma unroll
  for (int i = 0; i < 4; ++i) {
    double pi = 0.0;
    #pragma unroll
    for (int j = 0; j < 4; ++j) {
      double cov = acc[i][j] - 16384.0 * mr[i] * mc[j];
      pi += fabs(cov) / dc[j];
    }
    red[ty * 4 + i][tx] = pi;
  }
  __syncthreads();
  if (t < 64) {
    double ssum = 0.0;
    #pragma unroll
    for (int q = 0; q < 16; ++q) ssum += red[t][q];
    fpart[(size_t)(bi * 64 + t) * 16 + bj] = ssum;
  }
}

// ---------------- K3: per-row histogram (float32 np binning) + local entropy ----------------
__global__ __launch_bounds__(256) void k_hist(const float* __restrict__ x,
    const float* __restrict__ fscal, double* __restrict__ localent,
    unsigned* __restrict__ bc) {
#pragma clang fp contract(off)
  __shared__ unsigned h[BINS];
  const int row = blockIdx.x, t = threadIdx.x;
  for (int b = t; b < BINS; b += 256) h[b] = 0;
  __syncthreads();
  const float mu32 = fscal[0], sg32 = fscal[1], lof = fscal[2], wf = fscal[3];
  const float4* xr = (const float4*)(x + (size_t)row * DCOLS);
  for (int j = t; j < DCOLS / 4; j += 256) {
    float4 v = xr[j];
    float vv[4] = {v.x, v.y, v.z, v.w};
    #pragma unroll
    for (int c = 0; c < 4; ++c) {
      float tn = (vv[c] - mu32) / sg32;   // float32 ops, exactly as np
      float q  = (tn - lof) / wf;
      int idx = (int)floorf(q);
      idx = idx < 0 ? 0 : (idx > BINS - 1 ? BINS - 1 : idx);
      atomicAdd(&h[idx], 1u);
    }
  }
  __syncthreads();
  const double Dw = (double)fscal[4];   // float32 n*width, promoted
  double ls = 0.0;
  for (int b = t; b < BINS; b += 256) {
    unsigned c = h[b];
    if (c) {
      atomicAdd(&bc[b], c);
      double pd = (double)c / Dw;
      ls -= pd * log2(pd);
    }
  }
  #pragma unroll
  for (int off = 32; off > 0; off >>= 1) ls += __shfl_down(ls, off);
  __shared__ double lsd[4];
  const int lane = t & 63, w = t >> 6;
  if (lane == 0) lsd[w] = ls;
  __syncthreads();
  if (t == 0) localent[row] = (lsd[0] + lsd[1]) + (lsd[2] + lsd[3]);
}

// ---------------- K4: batch entropy + per-row pf / keepf (float32 np chain) ----------------
__global__ __launch_bounds__(256) void k_final(const unsigned* __restrict__ bc,
    const float* __restrict__ fscal, const double* __restrict__ localent,
    const double* __restrict__ fpart, const double* __restrict__ dn,
    float* __restrict__ pf, float* __restrict__ kf) {
#pragma clang fp contract(off)
  const int t = threadIdx.x;
  const double Nw = (double)fscal[5];
  double be = 0.0;
  for (int b = t; b < BINS; b += 256) {
    unsigned c = bc[b];
    if (c) { double pd = (double)c / Nw; be -= pd * log2(pd); }
  }
  #pragma unroll
  for (int off = 32; off > 0; off >>= 1) be += __shfl_down(be, off);
  __shared__ double lsd[4];
  __shared__ double sbent;
  const int lane = t & 63, w = t >> 6;
  if (lane == 0) lsd[w] = be;
  __syncthreads();
  if (t == 0) sbent = (lsd[0] + lsd[1]) + (lsd[2] + lsd[3]);
  __syncthreads();
  const float bef = (float)sbent;
  for (int r = t; r < NROWS; r += 256) {
    double s = 0.0;
    #pragma unroll
    for (int q = 0; q < 16; ++q) s += fpart[(size_t)r * 16 + q];
    float f1f = (float)(s / (dn[r] * 1024.0));
    float lef = (float)localent[r];
    float f2f = lef / bef;                   // float32 division, as np
    if (f2f == 0.0f) { f1f = 0.0f; f2f = 1.0f; }
    else if (f2f < 1.0f) f2f = 1.0f / f2f;
    float keepf = f1f / f2f;
    pf[r] = 1.0f - keepf;
    kf[r] = keepf;
  }
}

// ---------------- K6: elementwise masked scale (float32 compare + division) ----------------
__global__ __launch_bounds__(256) void k_apply(const float* __restrict__ x,
    const float* __restrict__ u, const float* __restrict__ pf,
    const float* __restrict__ kf, float* __restrict__ out) {
#pragma clang fp contract(off)
  const size_t e = ((size_t)blockIdx.x * 256 + threadIdx.x) * 4;
  const int row = (int)(e >> 14);
  const float pr = pf[row], kr = kf[row];
  const float4 xv = *(const float4*)(x + e);
  const float4 uv = *(const float4*)(u + e);
  float4 o;
  o.x = (uv.x > pr) ? (xv.x / kr) : 0.0f;
  o.y = (uv.y > pr) ? (xv.y / kr) : 0.0f;
  o.z = (uv.z > pr) ? (xv.z / kr) : 0.0f;
  o.w = (uv.w > pr) ? (xv.w / kr) : 0.0f;
  *(float4*)(out + e) = o;
}

extern "C" void kernel_launch(void* const* d_in, const int* in_sizes, int n_in,
                              void* d_out, int out_size, void* d_ws, size_t ws_size,
                              hipStream_t stream) {
  const float* x = (const float*)d_in[0];
  const float* u = (const float*)d_in[1];
  float* out = (float*)d_out;

  double* W = (double*)d_ws;
  double* rowsum   = W;
  double* rowsumsq = W + 1024;
  double* rowmin   = W + 2048;
  double* rowmax   = W + 3072;
  double* m        = W + 4096;
  double* dn       = W + 5120;
  double* localent = W + 6144;
  double* fpart    = W + 7168;               // 1024*16 doubles
  float*  F        = (float*)(W + 7168 + 16384);
  float*  pf       = F;                      // 1024 floats
  float*  kf       = F + 1024;               // 1024 floats
  float*  fscal    = F + 2048;               // 8 floats
  unsigned* bc     = (unsigned*)(F + 2056);  // 1000 uints

  hipMemsetAsync(bc, 0, BINS * sizeof(unsigned), stream);

  k_rowstats<<<NROWS, 256, 0, stream>>>(x, rowsum, rowsumsq, rowmin, rowmax);
  k_stats2<<<1, 256, 0, stream>>>(rowsum, rowsumsq, rowmin, rowmax, m, dn, fscal);
  k_gram<<<dim3(16, 16), 256, 0, stream>>>(x, m, dn, fpart);
  k_hist<<<NROWS, 256, 0, stream>>>(x, fscal, localent, bc);
  k_final<<<1, 256, 0, stream>>>(bc, fscal, localent, fpart, dn, pf, kf);
  k_apply<<<NTOT / (256 * 4), 256, 0, stream>>>(x, u, pf, kf, out);
}